// Round 7
// baseline (200.934 us; speedup 1.0000x reference)
//
#include <hip/hip_runtime.h>

// Axial 7x7 attention, fused. N=512, GRID=7, Cq=64, Cv=512, B=3584.
// Round-7: drop V LDS-staging entirely (guide CM#7). PV reads V directly from
// global: thread (g,hw) needs 28 CONTIGUOUS aligned floats per quad
// (vH[n,w,c..c+3,:] = base + w*3584 + c*7), and the only reuse (7 lanes, same
// w / different h) is intra-wave -> coalescer dedups it at issue; LDS bought
// nothing. This deletes all 16 PV barriers, all v ds_write/ds_read traffic
// (~46K cyc/CU of LDS port), and the staging instructions. PV becomes a
// barrier-free load->FMA->store stream; 16 waves/CU x 28 independent loads
// hide latency via TLP (r6 proved counted-vmcnt pipelining of the staged
// version buys 0 -- the bulk-synchronous structure was the cost, not the
// drains). Prologue (kT gather -> logits -> softmax, 3 barriers) unchanged;
// LDS 30.4KB. Grid 512, one n per block (r5: c-split duplicates prologue).
// (512,4): 128-VGPR budget; occupancy is grid-capped at 2 blocks/CU anyway.

#define NEGINF (-1e20f)

constexpr int QK_SLICE = 7 * 7 * 64;    // 3136 floats per n (q/k arrays)
constexpr int V_SLICE  = 7 * 512 * 7;   // 25088 floats per n (v arrays / out)

__device__ __forceinline__ void g2l4(const float* g, float* l) {
    __builtin_amdgcn_global_load_lds(
        (const __attribute__((address_space(1))) void*)g,
        (__attribute__((address_space(3))) void*)l, 4, 0, 0);
}

__global__ __launch_bounds__(512, 4) void fused_axial(
    const float* __restrict__ qH, const float* __restrict__ kH,
    const float* __restrict__ vH, const float* __restrict__ qW,
    const float* __restrict__ kW, const float* __restrict__ vW,
    float* __restrict__ out)
{
    // LDS (dwords): kTH = R+0 (3388, [a][j][c] strides 484/68), kTW = R+3388,
    // P = sm+6776 (49 rows x stride 17, 833). Total 7609 dw = 30436 B.
    __shared__ float sm[7609];
    float* R = sm;
    float* P = sm + 6776;

    const int n    = blockIdx.x;
    const int t    = threadIdx.x;
    const int lane = t & 63;
    const int wv   = t >> 6;                          // wave 0..7

    const float* qHn = qH + n * QK_SLICE;
    const float* kHn = kH + n * QK_SLICE;
    const float* qWn = qW + n * QK_SLICE;
    const float* kWn = kW + n * QK_SLICE;
    const float* vHn = vH + n * V_SLICE;
    const float* vWn = vW + n * V_SLICE;
    float* outn = out + n * V_SLICE;

    // ---- Phase K: gather-stage kT[arr][a][j][c] (98 insts, 8 waves) ----
    #pragma unroll
    for (int u = 0; u < 13; ++u) {
        const int r = wv + 8 * u;
        if (u < 12 || r < 98) {
            const int arr = r >= 49;
            const int wj  = r - 49 * arr;
            const int a   = (wj * 37) >> 8;           // wj/7
            const int j   = wj - 7 * a;
            const float* src = (arr ? kWn : kHn) + a * 448 + lane * 7 + j;
            float* dst = R + arr * 3388 + a * 484 + j * 68;   // + lane*4 implicit
            g2l4(src, dst);
        }
    }
    __syncthreads();   // kT staged (barrier drains vmcnt)

    // ---- Phase L: logits. wave -> (arr,a) group, lane -> (b,j) ----
    {
        const int b = lane >> 3;
        const int j = lane & 7;
        auto logit_group = [&](int gi) {
            const int arr = gi >= 7;
            const int a   = gi - 7 * arr;
            if (b < 7 && j < 7) {
                const float* qrow = (arr ? qWn : qHn) + (a * 7 + b) * 64;
                const float* krow = R + arr * 3388 + a * 484 + j * 68;
                float e = 0.f;
                #pragma unroll
                for (int cc = 0; cc < 64; cc += 4) {
                    float4 qv = *(const float4*)(qrow + cc);
                    float4 kv = *(const float4*)(krow + cc);
                    e += qv.x * kv.x + qv.y * kv.y + qv.z * kv.z + qv.w * kv.w;
                }
                if (!arr) {
                    if (b == j) e = NEGINF;           // diagonal mask (h==j)
                    P[(b * 7 + a) * 17 + j] = e;      // logits[h=b, w=a, j]
                } else {
                    P[(a * 7 + b) * 17 + 7 + j] = e;  // logits[h=a, w=b, 7+y]
                }
            }
        };
        logit_group(wv);
        if (wv < 6) logit_group(wv + 8);
    }
    __syncthreads();   // logits in P

    // ---- Phase S: softmax over 14 per (h,w) ----
    if (t < 49) {
        float* row = P + t * 17;
        float l[14];
        float m = -3.4e38f;
        #pragma unroll
        for (int k = 0; k < 14; ++k) { l[k] = row[k]; m = fmaxf(m, l[k]); }
        float s = 0.f;
        #pragma unroll
        for (int k = 0; k < 14; ++k) { l[k] = __expf(l[k] - m); s += l[k]; }
        float inv = 1.f / s;
        #pragma unroll
        for (int k = 0; k < 14; ++k) row[k] = l[k] * inv;
    }
    __syncthreads();   // P final

    // ---- Phase PV: barrier-free, V direct from global ----
    const int g  = (t * 1339) >> 16;     // t/49
    const int hw = t - g * 49;
    const int h  = (hw * 37) >> 8;
    const int w  = hw - 7 * h;

    if (t < 490) {
        float pr[14];
        #pragma unroll
        for (int k = 0; k < 14; ++k) pr[k] = P[hw * 17 + k];

        const float* baseA = vHn + w * 3584;   // vH row w: [c][j], c-contiguous
        const float* baseB = vWn + h * 3584;   // vW row h

        for (int chunk = 0; chunk < 8; ++chunk) {
            #pragma unroll
            for (int it = 0; it < 2; ++it) {
                if (it == 0 || g < 6) {
                    const int quad = g + 10 * it;            // 0..15
                    const int coff = (chunk * 64 + quad * 4) * 7;  // 16B-aligned
                    const float* ra = baseA + coff;
                    const float* rb = baseB + coff;
                    float ac[4] = {0.f, 0.f, 0.f, 0.f};
                    #pragma unroll
                    for (int q = 0; q < 7; ++q) {
                        float4 f = *(const float4*)(ra + 4 * q);
                        ac[(4 * q + 0) / 7] += pr[(4 * q + 0) % 7] * f.x;
                        ac[(4 * q + 1) / 7] += pr[(4 * q + 1) % 7] * f.y;
                        ac[(4 * q + 2) / 7] += pr[(4 * q + 2) % 7] * f.z;
                        ac[(4 * q + 3) / 7] += pr[(4 * q + 3) % 7] * f.w;
                    }
                    #pragma unroll
                    for (int q = 0; q < 7; ++q) {
                        float4 f = *(const float4*)(rb + 4 * q);
                        ac[(4 * q + 0) / 7] += pr[7 + (4 * q + 0) % 7] * f.x;
                        ac[(4 * q + 1) / 7] += pr[7 + (4 * q + 1) % 7] * f.y;
                        ac[(4 * q + 2) / 7] += pr[7 + (4 * q + 2) % 7] * f.z;
                        ac[(4 * q + 3) / 7] += pr[7 + (4 * q + 3) % 7] * f.w;
                    }
                    float* o = outn + (chunk * 64 + quad * 4) * 49 + hw;
                    o[0]   = ac[0];
                    o[49]  = ac[1];
                    o[98]  = ac[2];
                    o[147] = ac[3];
                }
            }
        }
    }
}

extern "C" void kernel_launch(void* const* d_in, const int* in_sizes, int n_in,
                              void* d_out, int out_size, void* d_ws, size_t ws_size,
                              hipStream_t stream) {
    const float* qH = (const float*)d_in[0];
    const float* kH = (const float*)d_in[1];
    const float* vH = (const float*)d_in[2];
    const float* qW = (const float*)d_in[3];
    const float* kW = (const float*)d_in[4];
    const float* vW = (const float*)d_in[5];
    float* out = (float*)d_out;
    fused_axial<<<512, 512, 0, stream>>>(qH, kH, vH, qW, kW, vW, out);
}